// Round 1
// baseline (366.431 us; speedup 1.0000x reference)
//
#include <hip/hip_runtime.h>

// Conv4d: x(2,8,16,40,40,40) f32 * w(3,32,8,3,3,3) + bias(3,32) -> out(2,32,16,40,40,40) f32
// Round 3: A-fragments (weights) moved LDS -> global/L1-resident register loads.
//   prep_x: x -> x_t[b][t][dp 42][hp 42][wp 42][ci 8] bf16, zero-padded d/h/w (+1 halo), in d_ws.
//   prep_w: weights -> exact A-fragment order Wf[kt][s 7][mt 2][lane 64][j 8] bf16 (K=216 pad 224).
//   main:   block=(b,o,d,h-tile8), 256 thr (4 waves); wave = 32co x 80n via mfma_f32_16x16x32_bf16.
//           A-frags read per-s directly from wf (L1-hot, coalesced 1024B/wave) -- no sWf LDS.
//           Halo (3d' x 10h' x 42w' x 8ci = 20160B) staged via global_load_lds width 16.

typedef unsigned int u32;
typedef unsigned short u16;
typedef __attribute__((ext_vector_type(8))) short short8;
typedef __attribute__((ext_vector_type(4))) float f32x4;

#define XT_OFF_BYTES 65536
// x_t strides in elements (bf16): ci 1, wp 8, hp 336, dp 14112, t 592704, b 9483264

__device__ __forceinline__ u32 bf16r(float f) {
    u32 u = __float_as_uint(f);
    return (u + 0x7FFFu + ((u >> 16) & 1u)) >> 16;
}

__device__ __forceinline__ void glds16(const void* g, void* l) {
    __builtin_amdgcn_global_load_lds((const __attribute__((address_space(1))) u32*)g,
                                     (__attribute__((address_space(3))) u32*)l, 16, 0, 0);
}

// ---------- pre-kernel A: transpose/pad/convert x ----------
__global__ __launch_bounds__(256) void prep_x(const float* __restrict__ x, u16* __restrict__ xtp) {
    const int c = blockIdx.x * 256 + threadIdx.x;        // cell over [b][t][dp][hp][wp], 2370816 total
    int wp = c % 42;
    int tmp = c / 42;
    const int hp = tmp % 42; tmp /= 42;
    const int dp = tmp % 42; tmp /= 42;
    const int t  = tmp % 16;
    const int b  = tmp / 16;
    const int wa = wp - 1, ha = hp - 1, da = dp - 1;
    u32 q0 = 0, q1 = 0, q2 = 0, q3 = 0;
    if ((unsigned)wa < 40u && (unsigned)ha < 40u && (unsigned)da < 40u) {
        const float* xp = x + ((b * 8) * 16 + t) * 64000 + da * 1600 + ha * 40 + wa;
        float v0 = xp[0];
        float v1 = xp[1024000];
        float v2 = xp[2048000];
        float v3 = xp[3072000];
        float v4 = xp[4096000];
        float v5 = xp[5120000];
        float v6 = xp[6144000];
        float v7 = xp[7168000];
        q0 = bf16r(v0) | (bf16r(v1) << 16);
        q1 = bf16r(v2) | (bf16r(v3) << 16);
        q2 = bf16r(v4) | (bf16r(v5) << 16);
        q3 = bf16r(v6) | (bf16r(v7) << 16);
    }
    uint4 q; q.x = q0; q.y = q1; q.z = q2; q.w = q3;
    *(uint4*)(xtp + (size_t)c * 8) = q;
}

// ---------- pre-kernel B: weights -> A-fragment order ----------
__global__ __launch_bounds__(256) void prep_w(const float* __restrict__ wgt, u16* __restrict__ wf) {
    const int idx = blockIdx.x * 256 + threadIdx.x;      // 21504 total = 3*14*512
    const int kt = idx / 7168;
    const int r  = idx - kt * 7168;
    const int s2 = r >> 9;              // s*2 + mt
    const int l  = (r >> 3) & 63;
    const int j  = r & 7;
    const int co = (s2 & 1) * 16 + (l & 15);
    const int k  = (s2 >> 1) * 32 + (l >> 4) * 8 + j;
    u32 v = 0;
    if (k < 216) {
        const int ci = k & 7;
        const int combo = k >> 3;                         // (kd,kh,kw)
        const int kd = combo / 9;
        const int r9 = combo - kd * 9;
        const int kh = r9 / 3;
        const int kw = r9 - kh * 3;
        v = bf16r(wgt[((kt * 32 + co) * 8 + ci) * 27 + kd * 9 + kh * 3 + kw]);
    }
    wf[idx] = (u16)v;
}

// ---------- main kernel ----------
__global__ __launch_bounds__(256, 4) void conv4d_mfma(
    const u16* __restrict__ xtp, const u16* __restrict__ wf,
    const float* __restrict__ bias, float* __restrict__ out)
{
    __shared__ __align__(16) u16 sHalo[10080];  // 20160 B: [d'3][h'10][w'42][ci8]
    __shared__ float sBsum[32];

    const int tid  = threadIdx.x;
    const int lane = tid & 63;
    const int wid  = tid >> 6;          // 0..3
    const int bi   = blockIdx.x;
    const int h0   = (bi % 5) * 8;
    const int d    = (bi / 5) % 40;
    const int o    = (bi / 200) % 16;
    const int b    = bi / 3200;

    if (tid < 32) {
        float s = 0.f;
        for (int kt = 0; kt < 3; ++kt) {
            int t = o + kt - 1;
            if ((unsigned)t < 16u) s += bias[kt * 32 + tid];
        }
        sBsum[tid] = s;
    }

    const int quad = lane >> 4;
    const int nl   = lane & 15;

    // per-lane n positions (5 n-tiles of 16, 80 n per wave)
    int lb[5];
#pragma unroll
    for (int tl = 0; tl < 5; ++tl) {
        int n = wid * 80 + tl * 16 + nl;   // 0..319
        int hh = n / 40;
        int ww = n - hh * 40;
        lb[tl] = (hh * 42 + ww) * 16;      // byte offset of cell (h'=hh, w'=ww) at d'=0
    }

    // per-lane combo offset per K-step (combo = 4s + quad), bytes
    int offs7[7];
#pragma unroll
    for (int s = 0; s < 7; ++s) {
        const int c0 = 4 * s;
        int O0 = (c0+0 < 27) ? (((c0+0)/9)*420 + (((c0+0)%9)/3)*42 + ((c0+0)%3)) * 16 : 0;
        int O1 = (c0+1 < 27) ? (((c0+1)/9)*420 + (((c0+1)%9)/3)*42 + ((c0+1)%3)) * 16 : 0;
        int O2 = (c0+2 < 27) ? (((c0+2)/9)*420 + (((c0+2)%9)/3)*42 + ((c0+2)%3)) * 16 : 0;
        int O3 = (c0+3 < 27) ? (((c0+3)/9)*420 + (((c0+3)%9)/3)*42 + ((c0+3)%3)) * 16 : 0;
        offs7[s] = (quad & 2) ? ((quad & 1) ? O3 : O2) : ((quad & 1) ? O1 : O0);
    }

    const f32x4 zero = {0.f, 0.f, 0.f, 0.f};
    f32x4 acc[2][5];
#pragma unroll
    for (int mt = 0; mt < 2; ++mt)
#pragma unroll
        for (int tl = 0; tl < 5; ++tl) acc[mt][tl] = zero;

#pragma unroll
    for (int kt = 0; kt < 3; ++kt) {
        const int t = o + kt - 1;

        __syncthreads();   // previous iteration's LDS reads done (block-uniform)
        if ((unsigned)t >= 16u) continue;            // block-uniform

        // stage halo: 1260 x 16B chunks; rows (d',h') contiguous per d' (420 chunks each)
        {
            const u16* gbase = xtp + (size_t)(b * 16 + t) * 592704 + h0 * 336;
            const int jw = wid * 315;
#pragma unroll
            for (int i = 0; i < 5; ++i) {
                const int j = jw + i * 64 + lane;
                if (i < 4 || lane < 59) {
                    const int dpp = j / 420;       // 0..2
                    const int r = j - dpp * 420;
                    glds16(gbase + (d + dpp) * 14112 + r * 8, (char*)sHalo + (jw + i * 64) * 16);
                }
            }
        }
        __syncthreads();

        // K-loop: 7 steps of K=32 (4 combos/step); A-frags direct from global (L1-hot)
        const u16* wfk = wf + kt * 7168;
#pragma unroll
        for (int s = 0; s < 7; ++s) {
            const short8 a0 = *(const short8*)(wfk + s * 1024 + lane * 8);
            const short8 a1 = *(const short8*)(wfk + s * 1024 + 512 + lane * 8);
            const int off = offs7[s];
#pragma unroll
            for (int tl = 0; tl < 5; ++tl) {
                const short8 bf = *(const short8*)((const char*)sHalo + lb[tl] + off);
                acc[0][tl] = __builtin_amdgcn_mfma_f32_16x16x32_bf16(a0, bf, acc[0][tl], 0, 0, 0);
                acc[1][tl] = __builtin_amdgcn_mfma_f32_16x16x32_bf16(a1, bf, acc[1][tl], 0, 0, 0);
            }
        }
    }

    // epilogue: C/D layout col=lane&15 (n), row=quad*4+reg (co within 16-tile)
    const int coB = quad * 4;
    float bs[2][4];
#pragma unroll
    for (int mt = 0; mt < 2; ++mt)
#pragma unroll
        for (int reg = 0; reg < 4; ++reg) bs[mt][reg] = sBsum[mt * 16 + coB + reg];

#pragma unroll
    for (int mt = 0; mt < 2; ++mt)
#pragma unroll
        for (int tl = 0; tl < 5; ++tl) {
            int n = wid * 80 + tl * 16 + nl;
            int hh = n / 40;
            int ww = n - hh * 40;
            const size_t base = (size_t)(((b * 32 + mt * 16 + coB) * 16 + o)) * 64000
                              + d * 1600 + (h0 + hh) * 40 + ww;
#pragma unroll
            for (int reg = 0; reg < 4; ++reg)
                out[base + (size_t)reg * 1024000] = acc[mt][tl][reg] + bs[mt][reg];
        }
}

extern "C" void kernel_launch(void* const* d_in, const int* in_sizes, int n_in,
                              void* d_out, int out_size, void* d_ws, size_t ws_size,
                              hipStream_t stream)
{
    const float* x    = (const float*)d_in[0];
    const float* wgt  = (const float*)d_in[1];
    const float* bias = (const float*)d_in[2];
    float* out = (float*)d_out;
    u16* wfbuf = (u16*)d_ws;                                  // 43008 B
    u16* xtp   = (u16*)((char*)d_ws + XT_OFF_BYTES);          // 37,933,056 B
    (void)in_sizes; (void)n_in; (void)out_size; (void)ws_size;

    prep_w<<<dim3(84),   dim3(256), 0, stream>>>(wgt, wfbuf);
    prep_x<<<dim3(9261), dim3(256), 0, stream>>>(x, xtp);
    conv4d_mfma<<<dim3(6400), dim3(256), 0, stream>>>(xtp, wfbuf, bias, out);
}